// Round 3
// baseline (3574.086 us; speedup 1.0000x reference)
//
#include <hip/hip_runtime.h>
#include <hip/hip_fp16.h>

typedef _Float16 half8 __attribute__((ext_vector_type(8)));
typedef float floatx4 __attribute__((ext_vector_type(4)));

#define T_STEPS 30
#define BATCH   256
#define HID     1024
#define LAYERS  4
#define N4H     4096
#define K2      2048

__device__ __forceinline__ float sigm(float x)  { return 1.f / (1.f + __expf(-x)); }
__device__ __forceinline__ float ftanh(float x) { return 1.f - 2.f / (__expf(2.f * x) + 1.f); }

// ---------- one-time prep: weights [L][H][4H] f32 (kernel & rec_kernel)
// -> WRt [L][4096 q][2048 k] f16, transposed, with gate-grouped rows:
// q = (u>>4)*64 + gate*16 + (u&15)  (u = hidden unit, gate = i/f/g/o),
// W in k[0,1024), R in k[1024,2048). A 64-row q-group = 16 units x 4 gates.
__global__ void transpose_weights(const float* __restrict__ Wk,
                                  const float* __restrict__ Wr,
                                  _Float16* __restrict__ wrt) {
    __shared__ float tile[32][33];
    const int zc = blockIdx.z;          // 0..7 = layer*2 + mat
    const int j = zc >> 1, mat = zc & 1;
    const float* src = (mat == 0 ? Wk : Wr) + (size_t)j * HID * N4H;
    _Float16* dst = wrt + (size_t)j * N4H * K2 + mat * HID;
    const int c0 = blockIdx.x * 32;     // source column tile (over 4H)
    const int k0 = blockIdx.y * 32;     // source row tile (over H = k dim)
    const int tx = threadIdx.x, ty = threadIdx.y;   // (32,8)
    #pragma unroll
    for (int i = ty; i < 32; i += 8)
        tile[i][tx] = src[(size_t)(k0 + i) * N4H + (c0 + tx)];
    __syncthreads();
    const int l    = ty * 32 + tx;      // 0..255
    const int rloc = l >> 3;            // 0..31 local source column
    const int kg   = l & 7;             // 0..7 k-group of 4
    const int c = c0 + rloc;            // c = gate*1024 + u
    const int g = c >> 10, u = c & (HID - 1);
    const int q = (u >> 4) * 64 + g * 16 + (u & 15);
    union { _Float16 h[4]; float2 f2; } pk;
    #pragma unroll
    for (int i = 0; i < 4; ++i)
        pk.h[i] = (_Float16)tile[kg * 4 + i][rloc];
    *(float2*)(dst + (size_t)q * K2 + k0 + kg * 4) = pk.f2;
}

// ---------- diagonal-batched fused LSTM cells, LDS-free direct-MFMA GEMM.
// grid (64, ncells): x = 64-row q group (16 units x 4 gates), y = cell on
// the anti-diagonal (t+j = diag). 256 threads = 4 waves, wave = 64m x 64q
// (4x4 acc of 16x16x32 f16 MFMA). A and B frags loaded straight from global
// (no LDS, no barriers); ring-3 register pipeline gives ~2 chunks lookahead.
// b-subtile b == gate b, so the epilogue needs no data movement at all.
__global__ __launch_bounds__(256, 1) void lstm_diag(
    const float*    __restrict__ inputs,  // [30][256][1024] f32
    _Float16*       __restrict__ c_act,   // [2 parity][4][256][1024] f16
    _Float16*       __restrict__ h_act,   // [2 parity][4][256][1024] f16
    const _Float16* __restrict__ WRt,     // [4][4096][2048] f16
    const float*    __restrict__ bias,    // [4][4096] f32 gate-major
    float*          __restrict__ c_master,// [4][256][1024] f32
    int diag, int packed_t, int packed_j)
{
    const int z = blockIdx.y;
    const int t = (packed_t >> (8 * z)) & 255;
    const int j = (packed_j >> (8 * z)) & 255;
    const size_t BH = (size_t)BATCH * HID;
    const int par = diag & 1, pp = par ^ 1;

    const float*    X32 = inputs + (size_t)t * BH;                       // j==0
    const _Float16* X16 = (j > 0) ? c_act + ((size_t)pp * LAYERS + (j - 1)) * BH : (const _Float16*)0;
    const _Float16* Hr  = h_act + ((size_t)pp * LAYERS + j) * BH;
    const _Float16* WR  = WRt + (size_t)j * N4H * K2;
    const float* bias_j = bias + (size_t)j * N4H;

    const int tid  = threadIdx.x;
    const int wv   = tid >> 6, lane = tid & 63;
    const int quad = lane >> 4, l16 = lane & 15;
    const int mw = wv * 64;             // wave's m base (4 waves cover 256)
    const int q0 = blockIdx.x * 64;     // weight-row group base

    half8 af[3][2][4], bf[3][2][4];     // [ring][k-slice][subtile]
    floatx4 acc[4][4];                  // [m-subtile][gate]
    #pragma unroll
    for (int a = 0; a < 4; ++a)
        #pragma unroll
        for (int b = 0; b < 4; ++b)
            #pragma unroll
            for (int e = 0; e < 4; ++e) acc[a][b][e] = 0.f;

    auto load_chunk = [&](int kc, int r) {
        const _Float16* wp = WR + (size_t)q0 * K2 + kc + quad * 8;
        #pragma unroll
        for (int s = 0; s < 2; ++s)
            #pragma unroll
            for (int b = 0; b < 4; ++b)
                bf[r][s][b] = *(const half8*)(wp + (size_t)(b * 16 + l16) * K2 + s * 32);
        if (kc >= HID) {
            const _Float16* ap = Hr + (kc - HID) + quad * 8;
            #pragma unroll
            for (int s = 0; s < 2; ++s)
                #pragma unroll
                for (int a = 0; a < 4; ++a)
                    af[r][s][a] = *(const half8*)(ap + (size_t)(mw + a * 16 + l16) * HID + s * 32);
        } else if (j > 0) {
            const _Float16* ap = X16 + kc + quad * 8;
            #pragma unroll
            for (int s = 0; s < 2; ++s)
                #pragma unroll
                for (int a = 0; a < 4; ++a)
                    af[r][s][a] = *(const half8*)(ap + (size_t)(mw + a * 16 + l16) * HID + s * 32);
        } else {
            const float* ap = X32 + kc + quad * 8;
            #pragma unroll
            for (int s = 0; s < 2; ++s)
                #pragma unroll
                for (int a = 0; a < 4; ++a) {
                    const float* p = ap + (size_t)(mw + a * 16 + l16) * HID + s * 32;
                    const float4 lo = *(const float4*)p;
                    const float4 hi = *(const float4*)(p + 4);
                    half8 v;
                    v[0] = (_Float16)lo.x; v[1] = (_Float16)lo.y;
                    v[2] = (_Float16)lo.z; v[3] = (_Float16)lo.w;
                    v[4] = (_Float16)hi.x; v[5] = (_Float16)hi.y;
                    v[6] = (_Float16)hi.z; v[7] = (_Float16)hi.w;
                    af[r][s][a] = v;
                }
        }
    };

    load_chunk(0, 0);
    load_chunk(64, 1);
    load_chunk(128, 2);

    #pragma unroll
    for (int ic = 0; ic < 32; ++ic) {           // 32 chunks of 64 k
        const int r = ic % 3;
        #pragma unroll
        for (int s = 0; s < 2; ++s)
            #pragma unroll
            for (int a = 0; a < 4; ++a)
                #pragma unroll
                for (int b = 0; b < 4; ++b)
                    acc[a][b] = __builtin_amdgcn_mfma_f32_16x16x32_f16(
                        af[r][s][a], bf[r][s][b], acc[a][b], 0, 0, 0);
        if (ic + 3 < 32) load_chunk((ic + 3) * 64, r);
    }

    // ---- epilogue: acc[a][gate][e] holds z for m = mw+a*16+quad*4+e,
    // unit u = bx*16 + l16. No shuffles / LDS needed; stores coalesce (64B).
    const int u = blockIdx.x * 16 + l16;
    const float bi = bias_j[u];
    const float bff = bias_j[HID + u];
    const float bg = bias_j[2 * HID + u];
    const float bo = bias_j[3 * HID + u];
    float*    cm = c_master + (size_t)j * BH;
    _Float16* co = c_act + ((size_t)par * LAYERS + j) * BH;
    _Float16* ho = h_act + ((size_t)par * LAYERS + j) * BH;
    #pragma unroll
    for (int a = 0; a < 4; ++a)
        #pragma unroll
        for (int e = 0; e < 4; ++e) {
            const int m = mw + a * 16 + quad * 4 + e;
            const size_t idx = (size_t)m * HID + u;
            const float ig = sigm(acc[a][0][e] + bi);
            const float fg = sigm(acc[a][1][e] + bff);
            const float gg = ftanh(acc[a][2][e] + bg);
            const float og = sigm(acc[a][3][e] + bo);
            const float c = fg * cm[idx] + ig * gg;
            const float h = og * ftanh(c);
            cm[idx] = c;
            co[idx] = (_Float16)c;
            ho[idx] = (_Float16)h;
        }
}

extern "C" void kernel_launch(void* const* d_in, const int* in_sizes, int n_in,
                              void* d_out, int out_size, void* d_ws, size_t ws_size,
                              hipStream_t stream) {
    const float* inputs     = (const float*)d_in[0]; // [30,256,1024]
    const float* kernel_    = (const float*)d_in[1]; // [4,1024,4096]
    const float* rec_kernel = (const float*)d_in[2]; // [4,1024,4096]
    const float* bias       = (const float*)d_in[3]; // [4,4096]
    float* out = (float*)d_out;                      // [256,1024]

    char* ws = (char*)d_ws;
    _Float16* WRt      = (_Float16*)(ws);                 // 67,108,864 B
    float*    c_master = (float*)   (ws + 67108864);      //  4,194,304 B
    _Float16* c_act    = (_Float16*)(ws + 71303168);      //  4,194,304 B (2 parity)
    _Float16* h_act    = (_Float16*)(ws + 75497472);      //  4,194,304 B (2 parity)
    // total 79,691,776 B (< round-2's proven 93.3 MB)

    const size_t BH = (size_t)BATCH * HID;

    hipMemsetAsync(c_master, 0, LAYERS * BH * sizeof(float), stream);
    hipMemsetAsync(h_act, 0, 2 * LAYERS * BH * sizeof(_Float16), stream);

    transpose_weights<<<dim3(N4H / 32, HID / 32, LAYERS * 2), dim3(32, 8), 0, stream>>>(
        kernel_, rec_kernel, WRt);

    for (int d = 0; d < T_STEPS + LAYERS - 1; ++d) {
        const int jlo = (d - (T_STEPS - 1)) > 0 ? (d - (T_STEPS - 1)) : 0;
        const int jhi = d < (LAYERS - 1) ? d : (LAYERS - 1);
        const int nc  = jhi - jlo + 1;
        int pt = 0, pj = 0;
        for (int zz = 0; zz < nc; ++zz) {
            const int jj = jlo + zz, tt = d - jj;
            pt |= tt << (8 * zz);
            pj |= jj << (8 * zz);
        }
        lstm_diag<<<dim3(N4H / 64, nc), 256, 0, stream>>>(
            inputs, c_act, h_act, WRt, bias, c_master, d, pt, pj);
    }

    hipMemcpyAsync(out, c_master + 3 * BH, BH * sizeof(float),
                   hipMemcpyDeviceToDevice, stream);
}

// Round 4
// 1673.197 us; speedup vs baseline: 2.1361x; 2.1361x over previous
//
#include <hip/hip_runtime.h>
#include <hip/hip_fp16.h>

typedef _Float16 half8 __attribute__((ext_vector_type(8)));
typedef float floatx4 __attribute__((ext_vector_type(4)));

#define T_STEPS 30
#define BATCH   256
#define HID     1024
#define LAYERS  4
#define N4H     4096
#define K2      2048

#define BN 64          // q-rows per block (16 units x 4 gates)
#define BK 32          // k per chunk
#define NCHUNK (K2 / BK)

#define AS1(p) ((const __attribute__((address_space(1))) void*)(p))
#define AS3(p) ((__attribute__((address_space(3))) void*)(p))

__device__ __forceinline__ float sigm(float x)  { return 1.f / (1.f + __expf(-x)); }
__device__ __forceinline__ float ftanh(float x) { return 1.f - 2.f / (__expf(2.f * x) + 1.f); }

// ---------- weights [L][H][4H] f32 -> WRt [L][4096 q][2048 k] f16, transposed,
// gate-grouped rows q = (u>>4)*64 + gate*16 + (u&15); W k[0,1024), R k[1024,2048).
// 64x64 source tile per block, 256 threads.
__global__ __launch_bounds__(256) void transpose_weights(
    const float* __restrict__ Wk, const float* __restrict__ Wr,
    _Float16* __restrict__ wrt) {
    __shared__ float tile[64][65];      // 16.6 KB
    const int zc = blockIdx.z;          // layer*2 + mat
    const int j = zc >> 1, mat = zc & 1;
    const float* src = (mat == 0 ? Wk : Wr) + (size_t)j * HID * N4H;
    _Float16* dst = wrt + (size_t)j * N4H * K2 + mat * HID;
    const int c0 = blockIdx.x * 64;     // source columns (over 4H)
    const int k0 = blockIdx.y * 64;     // source rows (k dim)
    const int tid = threadIdx.x;
    const int r = tid >> 2, cq = (tid & 3) * 16;
    #pragma unroll
    for (int i = 0; i < 4; ++i) {
        const float4 v = *(const float4*)&src[(size_t)(k0 + r) * N4H + c0 + cq + i * 4];
        tile[r][cq + i * 4 + 0] = v.x; tile[r][cq + i * 4 + 1] = v.y;
        tile[r][cq + i * 4 + 2] = v.z; tile[r][cq + i * 4 + 3] = v.w;
    }
    __syncthreads();
    #pragma unroll
    for (int i = 0; i < 2; ++i) {
        const int s = i * 256 + tid;    // 0..511
        const int ql = s >> 3, kg = s & 7;
        const int c = c0 + ql, g = c >> 10, u = c & (HID - 1);
        const int q = ((u >> 4) << 6) + (g << 4) + (u & 15);
        union { _Float16 h[8]; int4 v; } pk;
        #pragma unroll
        for (int x = 0; x < 8; ++x)
            pk.h[x] = (_Float16)tile[kg * 8 + x][ql];
        *(int4*)(dst + (size_t)q * K2 + k0 + kg * 8) = pk.v;
    }
}

// ---------- inputs f32 -> f16
__global__ void cvt_inputs(const float* __restrict__ in, _Float16* __restrict__ out) {
    const size_t i = ((size_t)blockIdx.x * 256 + threadIdx.x) * 8;
    const float4 a = *(const float4*)(in + i);
    const float4 b = *(const float4*)(in + i + 4);
    half8 v;
    v[0] = (_Float16)a.x; v[1] = (_Float16)a.y; v[2] = (_Float16)a.z; v[3] = (_Float16)a.w;
    v[4] = (_Float16)b.x; v[5] = (_Float16)b.y; v[6] = (_Float16)b.z; v[7] = (_Float16)b.w;
    *(half8*)(out + i) = v;
}

// ---------- diagonal-batched fused LSTM cells.
// grid (64, ncells): x -> 64-row q group (16 units x 4 gates), y -> cell.
// Block = 256 threads = 4 waves; BM = 256 (whole batch), each wave owns a
// disjoint 64m x 64q tile (4x4 acc of 16x16x32 f16 MFMA, b-subtile == gate).
// Double-buffered LDS (ring 2 x [A 16KB | B 4KB]) staged via global_load_lds
// width=16; XOR swizzle g ^= (row>>1)&3 keeps ds_read_b128 at 2 lanes/bank.
// Loads for chunk k+1 issue BEFORE MFMA on chunk k so the vmcnt drain at the
// barrier overlaps compute. One barrier per chunk.
__global__ __launch_bounds__(256) void lstm_diag(
    const _Float16* __restrict__ Xf,      // [30][256][1024] f16
    _Float16*       __restrict__ c_act,   // [2 par][3][256][1024] f16 (layers 0..2)
    _Float16*       __restrict__ h_act,   // [2 par][4][256][1024] f16
    const _Float16* __restrict__ WRt,     // [4][4096][2048] f16
    const float*    __restrict__ bias,    // [4][4096] f32 gate-major
    float*          __restrict__ c_master,// [3][256][1024] f32 (layers 0..2)
    float*          __restrict__ c3,      // [256][1024] f32 == d_out (layer 3)
    int diag, int packed_t, int packed_j)
{
    const int z = blockIdx.y;
    const int t = (packed_t >> (8 * z)) & 255;
    const int j = (packed_j >> (8 * z)) & 255;
    const size_t BH = (size_t)BATCH * HID;
    const int par = diag & 1, pp = par ^ 1;

    const _Float16* Xsrc = (j == 0) ? Xf + (size_t)t * BH
                                    : c_act + ((size_t)pp * 3 + (j - 1)) * BH;
    const _Float16* Hr = h_act + ((size_t)pp * LAYERS + j) * BH;
    const _Float16* WR = WRt + (size_t)j * N4H * K2;
    const float* bias_j = bias + (size_t)j * N4H;

    // ring: [2][A 8192 halves | B 2048 halves] = 40960 B
    __shared__ __align__(16) _Float16 ring[2][8192 + 2048];

    const int tid  = threadIdx.x;
    const int wv   = tid >> 6, lane = tid & 63;
    const int quad = lane >> 4, l16 = lane & 15;
    const int wbase = wv * 64;
    const int mw = wv * 64;             // wave's m quadrant (4 waves cover 256)
    const int q0 = blockIdx.x * 64;

    floatx4 acc[4][4];                  // [m-subtile][gate]
    #pragma unroll
    for (int a = 0; a < 4; ++a)
        #pragma unroll
        for (int b = 0; b < 4; ++b)
            #pragma unroll
            for (int e = 0; e < 4; ++e) acc[a][b][e] = 0.f;

    auto stage = [&](int kc, int rb) {
        _Float16* Ab = ring[rb];
        _Float16* Bb = ring[rb] + 8192;
        // B first (HBM-latency critical): 256 granules, 1 inst/thread
        {
            const int s = tid;
            const int q = s >> 2, g = (s & 3) ^ ((q >> 1) & 3);
            __builtin_amdgcn_global_load_lds(
                AS1(WR + (size_t)(q0 + q) * K2 + kc + g * 8),
                AS3(Bb + wbase * 8), 16, 0, 0);
        }
        // A: 1024 granules (256 rows x 4), 4 insts/thread
        const _Float16* Ag = (kc < HID) ? Xsrc + kc : Hr + (kc - HID);
        #pragma unroll
        for (int i = 0; i < 4; ++i) {
            const int s = i * 256 + tid;
            const int r = s >> 2, g = (s & 3) ^ ((r >> 1) & 3);
            __builtin_amdgcn_global_load_lds(
                AS1(Ag + (size_t)r * HID + g * 8),
                AS3(Ab + (i * 256 + wbase) * 8), 16, 0, 0);
        }
    };

    auto compute = [&](int rb) {
        const _Float16* Ab = ring[rb];
        const _Float16* Bb = ring[rb] + 8192;
        half8 bf[4], af[4];
        #pragma unroll
        for (int b = 0; b < 4; ++b) {
            const int q = b * 16 + l16;
            bf[b] = *(const half8*)&Bb[((q << 2) + (quad ^ ((q >> 1) & 3))) * 8];
        }
        #pragma unroll
        for (int a = 0; a < 4; ++a) {
            const int r = mw + a * 16 + l16;
            af[a] = *(const half8*)&Ab[((r << 2) + (quad ^ ((r >> 1) & 3))) * 8];
        }
        #pragma unroll
        for (int a = 0; a < 4; ++a)
            #pragma unroll
            for (int b = 0; b < 4; ++b)
                acc[a][b] = __builtin_amdgcn_mfma_f32_16x16x32_f16(
                    af[a], bf[b], acc[a][b], 0, 0, 0);
    };

    stage(0, 0);
    __syncthreads();
    for (int ic = 0; ic < NCHUNK; ic += 2) {
        if (ic + 1 < NCHUNK) stage((ic + 1) * BK, 1);
        compute(0);
        __syncthreads();
        if (ic + 2 < NCHUNK) stage((ic + 2) * BK, 0);
        compute(1);
        __syncthreads();
    }

    // ---- epilogue: acc[a][gate][e] is z for m = mw + a*16 + quad*4 + e,
    // unit u = bx*16 + l16. Register-local gates, coalesced 32B stores.
    const int u = blockIdx.x * 16 + l16;
    const float bi = bias_j[u];
    const float bff = bias_j[HID + u];
    const float bg = bias_j[2 * HID + u];
    const float bo = bias_j[3 * HID + u];
    float* cm = (j == 3) ? c3 : c_master + (size_t)j * BH;
    _Float16* co = (j < 3) ? c_act + ((size_t)par * 3 + j) * BH : (_Float16*)0;
    _Float16* ho = h_act + ((size_t)par * LAYERS + j) * BH;
    #pragma unroll
    for (int a = 0; a < 4; ++a)
        #pragma unroll
        for (int e = 0; e < 4; ++e) {
            const int m = mw + a * 16 + quad * 4 + e;
            const size_t idx = (size_t)m * HID + u;
            const float ig = sigm(acc[a][0][e] + bi);
            const float fg = sigm(acc[a][1][e] + bff);
            const float gg = ftanh(acc[a][2][e] + bg);
            const float og = sigm(acc[a][3][e] + bo);
            const float c = fg * cm[idx] + ig * gg;
            const float h = og * ftanh(c);
            cm[idx] = c;
            if (j < 3) co[idx] = (_Float16)c;
            ho[idx] = (_Float16)h;
        }
}

extern "C" void kernel_launch(void* const* d_in, const int* in_sizes, int n_in,
                              void* d_out, int out_size, void* d_ws, size_t ws_size,
                              hipStream_t stream) {
    const float* inputs     = (const float*)d_in[0]; // [30,256,1024]
    const float* kernel_    = (const float*)d_in[1]; // [4,1024,4096]
    const float* rec_kernel = (const float*)d_in[2]; // [4,1024,4096]
    const float* bias       = (const float*)d_in[3]; // [4,4096]
    float* out = (float*)d_out;                      // [256,1024] == layer-3 c state

    char* ws = (char*)d_ws;
    _Float16* WRt      = (_Float16*)(ws);                 // 67,108,864 B
    _Float16* Xf       = (_Float16*)(ws + 67108864);      // 15,728,640 B
    float*    c_master = (float*)   (ws + 82837504);      //  3,145,728 B (layers 0..2)
    _Float16* c_act    = (_Float16*)(ws + 85983232);      //  3,145,728 B (2 par x 3 L)
    _Float16* h_act    = (_Float16*)(ws + 89128960);      //  4,194,304 B (2 par x 4 L)
    // total 93,323,264 B — the round-1/2 proven footprint

    const size_t BH = (size_t)BATCH * HID;

    hipMemsetAsync(c_master, 0, 3 * BH * sizeof(float), stream);
    hipMemsetAsync(h_act, 0, 2 * LAYERS * BH * sizeof(_Float16), stream);
    hipMemsetAsync(out, 0, BH * sizeof(float), stream);   // layer-3 c lives in d_out

    transpose_weights<<<dim3(N4H / 64, HID / 64, LAYERS * 2), 256, 0, stream>>>(
        kernel_, rec_kernel, WRt);
    cvt_inputs<<<(T_STEPS * BATCH * HID) / 8 / 256, 256, 0, stream>>>(inputs, Xf);

    for (int d = 0; d < T_STEPS + LAYERS - 1; ++d) {
        const int jlo = (d - (T_STEPS - 1)) > 0 ? (d - (T_STEPS - 1)) : 0;
        const int jhi = d < (LAYERS - 1) ? d : (LAYERS - 1);
        const int nc  = jhi - jlo + 1;
        int pt = 0, pj = 0;
        for (int zz = 0; zz < nc; ++zz) {
            const int jj = jlo + zz, tt = d - jj;
            pt |= tt << (8 * zz);
            pj |= jj << (8 * zz);
        }
        lstm_diag<<<dim3(N4H / BN, nc), 256, 0, stream>>>(
            Xf, c_act, h_act, WRt, bias, c_master, out, d, pt, pj);
    }
    // no final copy: out == layer-3 c_master, already holds c[3] at t=29
}